// Round 5
// baseline (451.015 us; speedup 1.0000x reference)
//
#include <hip/hip_runtime.h>
#include <math.h>

// Problem constants
#define BB 16
#define NN 1024
#define FF 128
#define NCG 64
#define NCONV 3
#define CAP 8

// ---- output layout (floats) ----
static const size_t O_M     = 0;
static const size_t O_MN    = (size_t)BB*NN*NCG;              // 1048576
static const size_t O_H     = O_MN  + (size_t)BB*NN*NCG;      // 2097152
static const size_t O_HH    = O_H   + (size_t)BB*NN*FF;       // 4194304
static const size_t O_ADJ   = O_HH  + (size_t)BB*NCG*FF;      // 4325376
static const size_t O_CGXYZ = O_ADJ + (size_t)BB*NN*NN;       // 21102592
static const size_t O_CGADJ = O_CGXYZ + (size_t)BB*NCG*3;     // 21105664
static const size_t O_KN    = O_CGADJ + (size_t)BB*NCG*NCG;   // 21171200

// f64 scratch aliased into adj output region (written last). adj = 8388608 doubles.
static const size_t S_H64  = 0;                                // [B*N*F]
static const size_t S_T64  = (size_t)BB*NN*FF;                 // 2097152 (t / ch buffer)
static const size_t S_LM64 = S_T64 + (size_t)BB*NN*FF;         // 4194304 (logits -> M)
static const size_t S_HPF  = 5242880;                          // 8 x [B*NCG*F] floats
static const size_t S_CGP  = 5767168;                          // 8 x [B*NCG*3] doubles
static const size_t S_NBR  = 6291456;                          // B*N*CAP ints
static const size_t S_W64  = 6553600;                          // 122880 doubles of f64 weights
// end: 6553600 + 122880 = 6676480 < 8388608  OK

// W64 internal offsets (doubles)
static const size_t WO_CGW1 = 98304;
static const size_t WO_CGW2 = 114688;
static const int    W64_N   = 122880;

// ---- ws layout (doubles) ----
static const size_t W_INVD = 0;                                // [B*N]
static const size_t W_COLS = (size_t)BB*NN;                    // [B*NCG]
static const size_t W_CG64 = W_COLS + (size_t)BB*NCG;          // [B*NCG*3]
static const size_t W_CNT  = W_CG64 + (size_t)BB*NCG*3;        // B*N ints

// ---------------- init ----------------
__global__ void k_zero(int* cnt) {
    int i = blockIdx.x * blockDim.x + threadIdx.x;
    if (i < BB*NN) cnt[i] = 0;
}

__global__ void k_build_nbr(const int* __restrict__ bonds, int nb, int* cnt, int* nbr) {
    int i = blockIdx.x * blockDim.x + threadIdx.x;
    if (i >= nb) return;
    int b = bonds[i*3+0], s = bonds[i*3+1], t = bonds[i*3+2];
    int ns = b*NN + s, nt = b*NN + t;
    int p = atomicAdd(&cnt[ns], 1);
    if (p < CAP) nbr[(size_t)ns*CAP + p] = nt;
    int q = atomicAdd(&cnt[nt], 1);
    if (q < CAP) nbr[(size_t)nt*CAP + q] = ns;
}

__global__ void k_invdeg(const int* __restrict__ cnt, double* invdeg) {
    int i = blockIdx.x * blockDim.x + threadIdx.x;
    if (i >= BB*NN) return;
    int d = cnt[i];
    invdeg[i] = d > 0 ? 1.0 / (double)d : 0.0;
}

__global__ void k_cgadj(float* cgadj) {
    int idx = blockIdx.x * blockDim.x + threadIdx.x;
    if (idx >= BB*NCG*NCG) return;
    int i = (idx / NCG) % NCG, j = idx % NCG;
    cgadj[idx] = (i == j) ? 0.f : 1.f;
}

__global__ void k_emb64(const int* __restrict__ atoms, const float* __restrict__ emb,
                        double* __restrict__ h) {
    int idx = blockIdx.x * blockDim.x + threadIdx.x;
    if (idx >= BB*NN*(FF/4)) return;
    int n = idx / (FF/4), f4 = idx % (FF/4);
    int a = atoms[n];
    const float4 v = *reinterpret_cast<const float4*>(&emb[(size_t)a*FF + f4*4]);
    double* hp = &h[(size_t)n*FF + f4*4];
    hp[0] = (double)v.x; hp[1] = (double)v.y; hp[2] = (double)v.z; hp[3] = (double)v.w;
}

// weights f32 -> f64, once
__global__ void k_cvtW(const float* __restrict__ uW1, const float* __restrict__ uW2,
                       const float* __restrict__ cgW1, const float* __restrict__ cgW2,
                       double* __restrict__ W64) {
    int idx = blockIdx.x * blockDim.x + threadIdx.x;
    if (idx >= W64_N) return;
    float v;
    if (idx < 98304) {
        int l = idx >> 15, r = idx & 32767;
        v = (r < 16384) ? uW1[l*16384 + r] : uW2[l*16384 + (r & 16383)];
    } else if (idx < 114688) {
        v = cgW1[idx - 98304];
    } else {
        v = cgW2[idx - 114688];
    }
    W64[idx] = (double)v;
}

// ---------------- f64 GEMM: out = act(in @ W + b), K=128 ----------------
// 32-row tiles (grid 512 -> 2 blocks/CU), full A tile staged once,
// W (pre-converted f64) staged per KC chunk with register prefetch.
// In-place (out == in) is safe: block reads only its own 32 rows, fully
// staged to LDS before the epilogue writes.
template<int COUT, bool TANH>
__global__ __launch_bounds__(256) void k_gemm64(const double* __restrict__ in,
                                                const double* __restrict__ W,
                                                const float* __restrict__ bias,
                                                double* __restrict__ out) {
    constexpr int K = 128, ROWS = 32, KC = 32;
    constexpr int ASTR = K + 2;               // row pad: break read conflicts
    constexpr int NW = KC*COUT/512;           // double2 staged per thread: 8 or 4
    constexpr int CT = COUT/8;                // 16 or 8 col-threads
    constexpr int RPT = ROWS*CT/256;          // 2 or 1 rows/thread
    __shared__ double As[ROWS*ASTR];          // 33.3 KB
    __shared__ double Ws[KC*COUT];            // 32 or 16 KB
    const int tid = threadIdx.x;
    const size_t row0 = (size_t)blockIdx.x * ROWS;
    const double2* in2 = reinterpret_cast<const double2*>(in + row0*K);
    const double2* Wg  = reinterpret_cast<const double2*>(W);
    double2* Ws2 = reinterpret_cast<double2*>(Ws);

    // stage full A tile: 32x128 doubles = 2048 double2
    #pragma unroll
    for (int i = 0; i < 8; ++i) {
        int q = tid + i*256;
        *reinterpret_cast<double2*>(&As[(q>>6)*ASTR + (q&63)*2]) = in2[q];
    }
    // prefetch W chunk 0 into registers
    double2 pW[NW];
    #pragma unroll
    for (int i = 0; i < NW; ++i) pW[i] = Wg[tid + i*256];

    const int tc = tid % CT, tr = tid / CT;
    const int r0 = tr * RPT;
    double acc[RPT][8];
    #pragma unroll
    for (int i = 0; i < RPT; ++i)
        #pragma unroll
        for (int j = 0; j < 8; ++j) acc[i][j] = 0.0;

    for (int kc = 0; kc < K; kc += KC) {
        __syncthreads();   // A staged (first iter) / prev Ws reads complete
        #pragma unroll
        for (int i = 0; i < NW; ++i) Ws2[tid + i*256] = pW[i];
        if (kc + KC < K) {
            #pragma unroll
            for (int i = 0; i < NW; ++i) pW[i] = Wg[(kc+KC)*(COUT/2) + tid + i*256];
        }
        __syncthreads();
        #pragma unroll
        for (int kk = 0; kk < KC; ++kk) {
            double a[RPT];
            #pragma unroll
            for (int i = 0; i < RPT; ++i) a[i] = As[(r0+i)*ASTR + kc + kk];
            const double2* wrow = reinterpret_cast<const double2*>(&Ws[kk*COUT]);
            #pragma unroll
            for (int g = 0; g < 4; ++g) {
                double2 u = wrow[tc + g*CT];
                #pragma unroll
                for (int i = 0; i < RPT; ++i) {
                    acc[i][g*2+0] += a[i]*u.x;
                    acc[i][g*2+1] += a[i]*u.y;
                }
            }
        }
    }

    #pragma unroll
    for (int g = 0; g < 4; ++g) {
        int c = tc*2 + g*(COUT/4);
        double b0 = (double)bias[c], b1 = (double)bias[c+1];
        #pragma unroll
        for (int i = 0; i < RPT; ++i) {
            double2 o;
            o.x = acc[i][g*2+0] + b0;
            o.y = acc[i][g*2+1] + b1;
            if (TANH) { o.x = tanh(o.x); o.y = tanh(o.y); }
            *reinterpret_cast<double2*>(&out[(row0 + r0 + i)*COUT + c]) = o;
        }
    }
}

// ---------------- gather: h[node,:] += invdeg[node] * sum_nbr ch[nbr,:] ----------------
template<bool WRITE_F32>
__global__ void k_gather(const double* __restrict__ ch, const double* __restrict__ invdeg,
                         const int* __restrict__ nbr, const int* __restrict__ cnt,
                         double* __restrict__ h, float* __restrict__ hout) {
    int idx = blockIdx.x * blockDim.x + threadIdx.x;
    if (idx >= BB*NN*(FF/4)) return;
    int node = idx >> 5, f4 = idx & 31;
    int c = cnt[node];
    double2 s0; s0.x = 0.0; s0.y = 0.0;
    double2 s1 = s0;
    for (int q = 0; q < c; ++q) {
        int nb = nbr[(size_t)node*CAP + q];
        const double2* cp = reinterpret_cast<const double2*>(ch + (size_t)nb*FF + f4*4);
        double2 a = cp[0], b2 = cp[1];
        s0.x += a.x; s0.y += a.y; s1.x += b2.x; s1.y += b2.y;
    }
    double w = invdeg[node];
    double2* hp = reinterpret_cast<double2*>(h + (size_t)node*FF + f4*4);
    double2 h0 = hp[0], h1 = hp[1];
    h0.x += s0.x*w; h0.y += s0.y*w; h1.x += s1.x*w; h1.y += s1.y*w;
    hp[0] = h0; hp[1] = h1;
    if (WRITE_F32) {
        float4 o; o.x = (float)h0.x; o.y = (float)h0.y; o.z = (float)h1.x; o.w = (float)h1.y;
        *reinterpret_cast<float4*>(&hout[(size_t)node*FF + f4*4]) = o;
    }
}

// ---------------- gumbel softmax (f64, in-place logits->M), no atomics ----------------
__global__ void k_softmax64(double* __restrict__ lm, const float* __restrict__ gum,
                            const float* __restrict__ tau_p, float* __restrict__ M_out) {
    int row = blockIdx.x * 4 + threadIdx.x / 64;
    int lane = threadIdx.x & 63;
    double tau = (double)(*tau_p);
    double u = (double)gum[(size_t)row*NCG + lane];
    double g = -log(-log(u));
    double v = (lm[(size_t)row*NCG + lane] + g) / tau;
    double m = v;
    #pragma unroll
    for (int off = 32; off; off >>= 1) m = fmax(m, __shfl_xor(m, off));
    double e = exp(v - m);
    double s = e;
    #pragma unroll
    for (int off = 32; off; off >>= 1) s += __shfl_xor(s, off);
    double mv = e / s;
    lm[(size_t)row*NCG + lane] = mv;
    M_out[(size_t)row*NCG + lane] = (float)mv;
}

// deterministic column sums: colsum[b,j] = sum_n M[b,n,j]
__global__ __launch_bounds__(256) void k_cols(const double* __restrict__ M,
                                              double* __restrict__ colsum) {
    __shared__ double red[256];
    int b = blockIdx.x;
    int tid = threadIdx.x;
    int j = tid & 63, q = tid >> 6;
    const double* Mb = M + (size_t)b*NN*NCG;
    double s = 0.0;
    for (int n = q*256; n < q*256 + 256; ++n) s += Mb[(size_t)n*NCG + j];
    red[tid] = s;
    __syncthreads();
    if (tid < 64) {
        colsum[b*NCG + j] = red[j] + red[64+j] + red[128+j] + red[192+j];
    }
}

__global__ void k_mnorm_out(const double* __restrict__ M, const double* __restrict__ colsum,
                            float* __restrict__ Mn) {
    size_t i = (size_t)blockIdx.x * blockDim.x + threadIdx.x;
    if (i >= (size_t)BB*NN*NCG) return;
    size_t b = i >> 16;
    int j = (int)(i & 63);
    Mn[i] = (float)(M[i] / colsum[b*NCG + j]);
}

// ---------------- H partials (f32): Hp[ch][b][j][f] = sum_{n in chunk} Mn[b,n,j] h[b,n,f] ----------------
__global__ __launch_bounds__(256) void k_Hpart32(const float* __restrict__ Mn,
                                                 const float* __restrict__ h,
                                                 float* __restrict__ Hp) {
    __shared__ float Ms[32*NCG];   // 8 KB
    __shared__ float hs[32*FF];    // 16 KB
    const int b = blockIdx.x, ch = blockIdx.y;
    const int tid = threadIdx.x;
    const int tc = tid % 32, tr = tid / 32;
    const float4* M4 = reinterpret_cast<const float4*>(Mn + (size_t)b*NN*NCG);
    const float4* h4 = reinterpret_cast<const float4*>(h + (size_t)b*NN*FF);
    float4* Ms4 = reinterpret_cast<float4*>(Ms);
    float4* hs4 = reinterpret_cast<float4*>(hs);
    const float2* Ms2 = reinterpret_cast<const float2*>(Ms);
    const float2* hs2 = reinterpret_cast<const float2*>(hs);

    float acc[8][4];
    #pragma unroll
    for (int i = 0; i < 8; ++i)
        #pragma unroll
        for (int j = 0; j < 4; ++j) acc[i][j] = 0.f;

    for (int s = 0; s < 4; ++s) {
        const int n0 = ch*128 + s*32;
        __syncthreads();
        #pragma unroll
        for (int i = 0; i < 2; ++i) Ms4[tid + i*256] = M4[n0*16 + tid + i*256];
        #pragma unroll
        for (int i = 0; i < 4; ++i) hs4[tid + i*256] = h4[n0*32 + tid + i*256];
        __syncthreads();
        for (int n = 0; n < 32; ++n) {
            float2 hv0 = hs2[n*64 + tc];
            float2 hv1 = hs2[n*64 + 32 + tc];
            float2 m0 = Ms2[n*32 + tr];
            float2 m1 = Ms2[n*32 + 8 + tr];
            float2 m2 = Ms2[n*32 + 16 + tr];
            float2 m3 = Ms2[n*32 + 24 + tr];
            float mj[8] = {m0.x, m0.y, m1.x, m1.y, m2.x, m2.y, m3.x, m3.y};
            #pragma unroll
            for (int jj = 0; jj < 8; ++jj) {
                acc[jj][0] += mj[jj]*hv0.x; acc[jj][1] += mj[jj]*hv0.y;
                acc[jj][2] += mj[jj]*hv1.x; acc[jj][3] += mj[jj]*hv1.y;
            }
        }
    }
    float* Ho = Hp + ((size_t)ch*BB + b) * NCG * FF;
    #pragma unroll
    for (int gj = 0; gj < 4; ++gj)
        #pragma unroll
        for (int pj = 0; pj < 2; ++pj) {
            int j = tr*2 + gj*16 + pj;
            int jj = gj*2 + pj;
            float2 o0; o0.x = acc[jj][0]; o0.y = acc[jj][1];
            float2 o1; o1.x = acc[jj][2]; o1.y = acc[jj][3];
            float2* op = reinterpret_cast<float2*>(Ho + (size_t)j*FF);
            op[tc] = o0; op[32 + tc] = o1;
        }
}

__global__ void k_Hfin32(const float* __restrict__ Hp, float* __restrict__ H) {
    int idx = blockIdx.x * blockDim.x + threadIdx.x;
    if (idx >= BB*NCG*FF) return;
    int b = idx / (NCG*FF);
    int r = idx % (NCG*FF);
    float s = 0.f;
    #pragma unroll
    for (int c = 0; c < 8; ++c) s += Hp[((size_t)c*BB + b)*NCG*FF + r];
    H[idx] = s;
}

// ---------------- cg partials (f64, feeds knbrs) ----------------
__global__ __launch_bounds__(192) void k_cgpart(const double* __restrict__ M,
                                                const float* __restrict__ xyz,
                                                double* __restrict__ cgp) {
    __shared__ double Ms[32*NCG];   // 16 KB
    __shared__ double xs[32*3];
    const int b = blockIdx.x, ch = blockIdx.y;
    const int tid = threadIdx.x;     // 192 = (j, d)
    const int j = tid / 3, d = tid % 3;
    const double2* M2 = reinterpret_cast<const double2*>(M + (size_t)b*NN*NCG);
    double2* Ms2 = reinterpret_cast<double2*>(Ms);
    const float* xb = xyz + (size_t)b*NN*3;
    double acc = 0.0;
    for (int s = 0; s < 4; ++s) {
        const int n0 = ch*128 + s*32;
        __syncthreads();
        for (int q = tid; q < 1024; q += 192) Ms2[q] = M2[n0*32 + q];
        for (int q = tid; q < 96; q += 192) xs[q] = (double)xb[n0*3 + q];
        __syncthreads();
        for (int n = 0; n < 32; ++n)
            acc += Ms[n*NCG + j] * xs[n*3 + d];
    }
    cgp[((size_t)ch*BB + b)*NCG*3 + tid] = acc;
}

__global__ void k_cgfin(const double* __restrict__ cgp, const double* __restrict__ colsum,
                        double* __restrict__ cg64, float* __restrict__ cg) {
    int idx = blockIdx.x * blockDim.x + threadIdx.x;
    if (idx >= BB*NCG*3) return;
    int b = idx / (NCG*3);
    int r = idx % (NCG*3);
    int j = r / 3;
    double s = 0.0;
    #pragma unroll
    for (int c = 0; c < 8; ++c) s += cgp[((size_t)c*BB + b)*NCG*3 + r];
    double v = s / colsum[b*NCG + j];
    cg64[idx] = v;
    cg[idx] = (float)v;
}

// ---------------- knbrs: rank-count argsort over squared distances ----------------
__global__ __launch_bounds__(1024) void k_knbrs(const double* __restrict__ cg,
                                                float* __restrict__ kn) {
    __shared__ double cs[NCG*3];
    const int b = blockIdx.x;
    const int tid = threadIdx.x;
    const int i = blockIdx.y * 16 + tid / 64;
    const int j = tid & 63;
    if (tid < NCG*3) cs[tid] = cg[(size_t)b*NCG*3 + tid];
    __syncthreads();
    double xi = cs[i*3+0], yi = cs[i*3+1], zi = cs[i*3+2];
    double dxj = xi - cs[j*3+0], dyj = yi - cs[j*3+1], dzj = zi - cs[j*3+2];
    double d2j = dxj*dxj + dyj*dyj + dzj*dzj;
    int rank = 0;
    for (int k = 0; k < NCG; ++k) {
        double dx = xi - cs[k*3+0], dy = yi - cs[k*3+1], dz = zi - cs[k*3+2];
        double d2k = dx*dx + dy*dy + dz*dz;
        rank += (d2k < d2j) || (d2k == d2j && k < j);
    }
    kn[(size_t)b*NCG*NCG + (size_t)i*NCG + rank] = (float)j;
}

// ---------------- adj (written LAST; region doubles as f64 scratch) ----------------
__global__ void k_zero_adj(float4* adj4, long n4) {
    long i = (long)blockIdx.x * blockDim.x + threadIdx.x;
    long stride = (long)gridDim.x * blockDim.x;
    float4 z; z.x = z.y = z.z = z.w = 0.f;
    for (; i < n4; i += stride) adj4[i] = z;
}

__global__ void k_bonds_adj(const int* __restrict__ bonds, int nb, float* adj) {
    int i = blockIdx.x * blockDim.x + threadIdx.x;
    if (i >= nb) return;
    int b = bonds[i*3+0], s = bonds[i*3+1], t = bonds[i*3+2];
    size_t base = (size_t)b * NN * NN;
    adj[base + (size_t)s*NN + t] = 1.f;
    adj[base + (size_t)t*NN + s] = 1.f;
}

extern "C" void kernel_launch(void* const* d_in, const int* in_sizes, int n_in,
                              void* d_out, int out_size, void* d_ws, size_t ws_size,
                              hipStream_t stream) {
    const int*   atoms  = (const int*)  d_in[0];
    const float* xyz    = (const float*)d_in[1];
    const int*   bonds  = (const int*)  d_in[2];
    const float* tau    = (const float*)d_in[3];
    const float* gum    = (const float*)d_in[4];
    const float* emb    = (const float*)d_in[5];
    const float* uW1    = (const float*)d_in[6];
    const float* ub1    = (const float*)d_in[7];
    const float* uW2    = (const float*)d_in[8];
    const float* ub2    = (const float*)d_in[9];
    const float* cgW1   = (const float*)d_in[10];
    const float* cgb1   = (const float*)d_in[11];
    const float* cgW2   = (const float*)d_in[12];
    const float* cgb2   = (const float*)d_in[13];

    float* out = (float*)d_out;
    float* o_M   = out + O_M;
    float* o_Mn  = out + O_MN;
    float* o_h   = out + O_H;
    float* o_H   = out + O_HH;
    float* o_adj = out + O_ADJ;
    float* o_cg  = out + O_CGXYZ;
    float* o_ca  = out + O_CGADJ;
    float* o_kn  = out + O_KN;

    double* scr  = (double*)o_adj;
    double* h64  = scr + S_H64;
    double* t64  = scr + S_T64;
    double* lm64 = scr + S_LM64;
    float*  Hpf  = (float*)(scr + S_HPF);
    double* cgp  = scr + S_CGP;
    int*    nbr  = (int*)(scr + S_NBR);
    double* W64  = scr + S_W64;

    double* wsd    = (double*)d_ws;
    double* invdeg = wsd + W_INVD;
    double* colsum = wsd + W_COLS;
    double* cg64   = wsd + W_CG64;
    int*    cnt    = (int*)(wsd + W_CNT);

    const int nb = in_sizes[2] / 3;

    hipLaunchKernelGGL(k_zero, dim3(64), dim3(256), 0, stream, cnt);
    hipLaunchKernelGGL(k_build_nbr, dim3((nb+255)/256), dim3(256), 0, stream,
                       bonds, nb, cnt, nbr);
    hipLaunchKernelGGL(k_invdeg, dim3(64), dim3(256), 0, stream, cnt, invdeg);
    hipLaunchKernelGGL(k_cgadj, dim3(256), dim3(256), 0, stream, o_ca);
    hipLaunchKernelGGL(k_cvtW, dim3((W64_N+255)/256), dim3(256), 0, stream,
                       uW1, uW2, cgW1, cgW2, W64);
    hipLaunchKernelGGL(k_emb64, dim3(2048), dim3(256), 0, stream, atoms, emb, h64);

    for (int l = 0; l < NCONV; ++l) {
        hipLaunchKernelGGL((k_gemm64<128,true>), dim3(512), dim3(256), 0, stream,
                           h64, W64 + (size_t)l*32768, ub1 + (size_t)l*FF, t64);
        hipLaunchKernelGGL((k_gemm64<128,false>), dim3(512), dim3(256), 0, stream,
                           t64, W64 + (size_t)l*32768 + 16384, ub2 + (size_t)l*FF, t64);
        if (l < NCONV-1)
            hipLaunchKernelGGL((k_gather<false>), dim3(2048), dim3(256), 0, stream,
                               t64, invdeg, nbr, cnt, h64, o_h);
        else
            hipLaunchKernelGGL((k_gather<true>), dim3(2048), dim3(256), 0, stream,
                               t64, invdeg, nbr, cnt, h64, o_h);
    }

    hipLaunchKernelGGL((k_gemm64<128,true>), dim3(512), dim3(256), 0, stream,
                       h64, W64 + WO_CGW1, cgb1, t64);
    hipLaunchKernelGGL((k_gemm64<64,false>), dim3(512), dim3(256), 0, stream,
                       t64, W64 + WO_CGW2, cgb2, lm64);

    hipLaunchKernelGGL(k_softmax64, dim3(4096), dim3(256), 0, stream,
                       lm64, gum, tau, o_M);
    hipLaunchKernelGGL(k_cols, dim3(16), dim3(256), 0, stream, lm64, colsum);
    hipLaunchKernelGGL(k_mnorm_out, dim3(4096), dim3(256), 0, stream, lm64, colsum, o_Mn);
    hipLaunchKernelGGL(k_Hpart32, dim3(BB, 8), dim3(256), 0, stream, o_Mn, o_h, Hpf);
    hipLaunchKernelGGL(k_Hfin32, dim3(512), dim3(256), 0, stream, Hpf, o_H);
    hipLaunchKernelGGL(k_cgpart, dim3(BB, 8), dim3(192), 0, stream, lm64, xyz, cgp);
    hipLaunchKernelGGL(k_cgfin, dim3(12), dim3(256), 0, stream, cgp, colsum, cg64, o_cg);
    hipLaunchKernelGGL(k_knbrs, dim3(BB, 4), dim3(1024), 0, stream, cg64, o_kn);

    // adj LAST: its region was scratch until here
    hipLaunchKernelGGL(k_zero_adj, dim3(4096), dim3(256), 0, stream,
                       (float4*)o_adj, (long)BB*NN*NN/4);
    hipLaunchKernelGGL(k_bonds_adj, dim3((nb+255)/256), dim3(256), 0, stream,
                       bonds, nb, o_adj);
}

// Round 6
// 399.816 us; speedup vs baseline: 1.1281x; 1.1281x over previous
//
#include <hip/hip_runtime.h>
#include <math.h>

// Problem constants
#define BB 16
#define NN 1024
#define FF 128
#define NCG 64
#define NCONV 3
#define CAP 8

// ---- output layout (floats) ----
static const size_t O_M     = 0;
static const size_t O_MN    = (size_t)BB*NN*NCG;              // 1048576
static const size_t O_H     = O_MN  + (size_t)BB*NN*NCG;      // 2097152
static const size_t O_HH    = O_H   + (size_t)BB*NN*FF;       // 4194304
static const size_t O_ADJ   = O_HH  + (size_t)BB*NCG*FF;      // 4325376
static const size_t O_CGXYZ = O_ADJ + (size_t)BB*NN*NN;       // 21102592
static const size_t O_CGADJ = O_CGXYZ + (size_t)BB*NCG*3;     // 21105664
static const size_t O_KN    = O_CGADJ + (size_t)BB*NCG*NCG;   // 21171200

// f64 scratch aliased into adj output region (written last). adj = 8388608 doubles.
static const size_t S_H64   = 0;         // [B*N*F] = 2M doubles
static const size_t S_T64   = 2097152;   // [B*N*F]
static const size_t S_C64   = 4194304;   // [B*N*F] (gemm2 output; NOT in-place)
static const size_t S_LM64  = 0;         // aliases h64 (dead by then): [B*N*NCG] = 1M
static const size_t S_COLSP = 4194304;   // aliases c64 (dead): 16*16*64 doubles
static const size_t S_HPF   = 6291456;   // 8 x [B*NCG*F] floats = 0.5M doubles
static const size_t S_CGP   = 6815744;   // 8 x [B*NCG*3] doubles = 24576
static const size_t S_NBR   = 6840320;   // B*N*CAP ints = 65536 doubles
static const size_t S_W64   = 6905856;   // 122880 doubles
// end 7028736 < 8388608 OK

// W64 internal offsets (doubles)
static const size_t WO_CGW1 = 98304;
static const size_t WO_CGW2 = 114688;
static const int    W64_N   = 122880;

// ---- ws layout (doubles) ----
static const size_t W_INVD = 0;                                // [B*N]
static const size_t W_COLS = (size_t)BB*NN;                    // [B*NCG]
static const size_t W_CG64 = W_COLS + (size_t)BB*NCG;          // [B*NCG*3]
static const size_t W_CNT  = W_CG64 + (size_t)BB*NCG*3;        // B*N ints

// ---------------- init ----------------
__global__ void k_zero(int* cnt) {
    int i = blockIdx.x * blockDim.x + threadIdx.x;
    if (i < BB*NN) cnt[i] = 0;
}

__global__ void k_build_nbr(const int* __restrict__ bonds, int nb, int* cnt, int* nbr) {
    int i = blockIdx.x * blockDim.x + threadIdx.x;
    if (i >= nb) return;
    int b = bonds[i*3+0], s = bonds[i*3+1], t = bonds[i*3+2];
    int ns = b*NN + s, nt = b*NN + t;
    int p = atomicAdd(&cnt[ns], 1);
    if (p < CAP) nbr[(size_t)ns*CAP + p] = nt;
    int q = atomicAdd(&cnt[nt], 1);
    if (q < CAP) nbr[(size_t)nt*CAP + q] = ns;
}

__global__ void k_invdeg(const int* __restrict__ cnt, double* invdeg) {
    int i = blockIdx.x * blockDim.x + threadIdx.x;
    if (i >= BB*NN) return;
    int d = cnt[i];
    invdeg[i] = d > 0 ? 1.0 / (double)d : 0.0;
}

__global__ void k_cgadj(float* cgadj) {
    int idx = blockIdx.x * blockDim.x + threadIdx.x;
    if (idx >= BB*NCG*NCG) return;
    int i = (idx / NCG) % NCG, j = idx % NCG;
    cgadj[idx] = (i == j) ? 0.f : 1.f;
}

__global__ void k_emb64(const int* __restrict__ atoms, const float* __restrict__ emb,
                        double* __restrict__ h) {
    int idx = blockIdx.x * blockDim.x + threadIdx.x;
    if (idx >= BB*NN*(FF/4)) return;
    int n = idx / (FF/4), f4 = idx % (FF/4);
    int a = atoms[n];
    const float4 v = *reinterpret_cast<const float4*>(&emb[(size_t)a*FF + f4*4]);
    double* hp = &h[(size_t)n*FF + f4*4];
    hp[0] = (double)v.x; hp[1] = (double)v.y; hp[2] = (double)v.z; hp[3] = (double)v.w;
}

// weights f32 -> f64, once
__global__ void k_cvtW(const float* __restrict__ uW1, const float* __restrict__ uW2,
                       const float* __restrict__ cgW1, const float* __restrict__ cgW2,
                       double* __restrict__ W64) {
    int idx = blockIdx.x * blockDim.x + threadIdx.x;
    if (idx >= W64_N) return;
    float v;
    if (idx < 98304) {
        int l = idx >> 15, r = idx & 32767;
        v = (r < 16384) ? uW1[l*16384 + r] : uW2[l*16384 + (r & 16383)];
    } else if (idx < 114688) {
        v = cgW1[idx - 98304];
    } else {
        v = cgW2[idx - 114688];
    }
    W64[idx] = (double)v;
}

// ---------------- f64 GEMM: out = act(in @ W + b), K=128 ----------------
// 64-row x 64-col blocks, 4x4 per thread, KC=32, register prefetch.
// grid = (rows/64, COUTT/64). Never in-place (col-split races otherwise).
template<int COUTT, bool TANH>
__global__ __launch_bounds__(256) void k_gemm64(const double* __restrict__ in,
                                                const double* __restrict__ W,
                                                const float* __restrict__ bias,
                                                double* __restrict__ out) {
    constexpr int K = 128, KC = 32;
    constexpr int CT2 = COUTT/2;              // W row stride (double2)
    __shared__ double As[64*34];              // 17.4 KB, rows interleaved tr+16i
    __shared__ double Ws[KC*64];              // 16 KB (this block's 64-col slice)
    const int tid = threadIdx.x;
    const int col0 = blockIdx.y * 64;
    const int C02 = col0 >> 1;
    const size_t row0 = (size_t)blockIdx.x * 64;
    const double2* in2 = reinterpret_cast<const double2*>(in + row0*K);
    const double2* Wg2 = reinterpret_cast<const double2*>(W);
    double2* As2 = reinterpret_cast<double2*>(As);
    double2* Ws2 = reinterpret_cast<double2*>(Ws);

    // prefetch chunk 0 into registers
    double2 pA[4], pW[4];
    #pragma unroll
    for (int i = 0; i < 4; ++i) { int q = tid + i*256; pA[i] = in2[(q>>4)*64 + (q&15)]; }
    #pragma unroll
    for (int i = 0; i < 4; ++i) { int q = tid + i*256; pW[i] = Wg2[(q>>5)*CT2 + C02 + (q&31)]; }

    const int tc = tid & 15, tr = tid >> 4;
    double acc[4][4];
    #pragma unroll
    for (int i = 0; i < 4; ++i)
        #pragma unroll
        for (int j = 0; j < 4; ++j) acc[i][j] = 0.0;

    for (int kc = 0; kc < K; kc += KC) {
        __syncthreads();   // prev chunk reads done
        #pragma unroll
        for (int i = 0; i < 4; ++i) { int q = tid + i*256; As2[(q>>4)*17 + (q&15)] = pA[i]; }
        #pragma unroll
        for (int i = 0; i < 4; ++i) { int q = tid + i*256; Ws2[(q>>5)*32 + (q&31)] = pW[i]; }
        if (kc + KC < K) {
            const int kn = kc + KC, kn2 = kn >> 1;
            #pragma unroll
            for (int i = 0; i < 4; ++i) { int q = tid + i*256; pA[i] = in2[(q>>4)*64 + kn2 + (q&15)]; }
            #pragma unroll
            for (int i = 0; i < 4; ++i) { int q = tid + i*256; pW[i] = Wg2[(kn + (q>>5))*CT2 + C02 + (q&31)]; }
        }
        __syncthreads();
        #pragma unroll
        for (int kk2 = 0; kk2 < KC/2; ++kk2) {
            double2 a[4];
            #pragma unroll
            for (int i = 0; i < 4; ++i) a[i] = As2[(tr + 16*i)*17 + kk2];
            const double2* w0 = Ws2 + (2*kk2+0)*32;
            const double2* w1 = Ws2 + (2*kk2+1)*32;
            #pragma unroll
            for (int g = 0; g < 2; ++g) {
                double2 u0 = w0[tc + g*16];
                double2 u1 = w1[tc + g*16];
                #pragma unroll
                for (int i = 0; i < 4; ++i) {
                    acc[i][g*2+0] += a[i].x*u0.x + a[i].y*u1.x;
                    acc[i][g*2+1] += a[i].x*u0.y + a[i].y*u1.y;
                }
            }
        }
    }

    #pragma unroll
    for (int g = 0; g < 2; ++g) {
        int c = col0 + tc*2 + g*32;
        double b0 = (double)bias[c], b1 = (double)bias[c+1];
        #pragma unroll
        for (int i = 0; i < 4; ++i) {
            double2 o;
            o.x = acc[i][g*2+0] + b0;
            o.y = acc[i][g*2+1] + b1;
            if (TANH) { o.x = tanh(o.x); o.y = tanh(o.y); }
            *reinterpret_cast<double2*>(&out[(row0 + tr + 16*i)*COUTT + c]) = o;
        }
    }
}

// ---------------- gather: h[node,:] += invdeg[node] * sum_nbr ch[nbr,:] ----------------
template<bool WRITE_F32>
__global__ void k_gather(const double* __restrict__ ch, const double* __restrict__ invdeg,
                         const int* __restrict__ nbr, const int* __restrict__ cnt,
                         double* __restrict__ h, float* __restrict__ hout) {
    int idx = blockIdx.x * blockDim.x + threadIdx.x;
    if (idx >= BB*NN*(FF/4)) return;
    int node = idx >> 5, f4 = idx & 31;
    int c = cnt[node];
    double2 s0; s0.x = 0.0; s0.y = 0.0;
    double2 s1 = s0;
    for (int q = 0; q < c; ++q) {
        int nb = nbr[(size_t)node*CAP + q];
        const double2* cp = reinterpret_cast<const double2*>(ch + (size_t)nb*FF + f4*4);
        double2 a = cp[0], b2 = cp[1];
        s0.x += a.x; s0.y += a.y; s1.x += b2.x; s1.y += b2.y;
    }
    double w = invdeg[node];
    double2* hp = reinterpret_cast<double2*>(h + (size_t)node*FF + f4*4);
    double2 h0 = hp[0], h1 = hp[1];
    h0.x += s0.x*w; h0.y += s0.y*w; h1.x += s1.x*w; h1.y += s1.y*w;
    hp[0] = h0; hp[1] = h1;
    if (WRITE_F32) {
        float4 o; o.x = (float)h0.x; o.y = (float)h0.y; o.z = (float)h1.x; o.w = (float)h1.y;
        *reinterpret_cast<float4*>(&hout[(size_t)node*FF + f4*4]) = o;
    }
}

// ---------------- gumbel softmax (f64, in-place logits->M), no atomics ----------------
__global__ void k_softmax64(double* __restrict__ lm, const float* __restrict__ gum,
                            const float* __restrict__ tau_p, float* __restrict__ M_out) {
    int row = blockIdx.x * 4 + threadIdx.x / 64;
    int lane = threadIdx.x & 63;
    double tau = (double)(*tau_p);
    double u = (double)gum[(size_t)row*NCG + lane];
    double g = -log(-log(u));
    double v = (lm[(size_t)row*NCG + lane] + g) / tau;
    double m = v;
    #pragma unroll
    for (int off = 32; off; off >>= 1) m = fmax(m, __shfl_xor(m, off));
    double e = exp(v - m);
    double s = e;
    #pragma unroll
    for (int off = 32; off; off >>= 1) s += __shfl_xor(s, off);
    double mv = e / s;
    lm[(size_t)row*NCG + lane] = mv;
    M_out[(size_t)row*NCG + lane] = (float)mv;
}

// deterministic chunked column sums: colsp[b,c,j] = sum_{n in chunk c} M[b,n,j]
__global__ __launch_bounds__(256) void k_cols_part(const double* __restrict__ M,
                                                   double* __restrict__ colsp) {
    __shared__ double red[256];
    const int b = blockIdx.x, c = blockIdx.y;
    const int tid = threadIdx.x;
    const int j = tid & 63, q = tid >> 6;
    const double* Mb = M + (size_t)b*NN*NCG + (size_t)(c*64 + q*16)*NCG;
    double s = 0.0;
    #pragma unroll
    for (int r = 0; r < 16; ++r) s += Mb[(size_t)r*NCG + j];
    red[tid] = s;
    __syncthreads();
    if (tid < 64)
        colsp[((size_t)b*16 + c)*NCG + j] = red[j] + red[64+j] + red[128+j] + red[192+j];
}

__global__ void k_cols_fin(const double* __restrict__ colsp, double* __restrict__ colsum) {
    int idx = blockIdx.x * blockDim.x + threadIdx.x;
    if (idx >= BB*NCG) return;
    int b = idx >> 6, j = idx & 63;
    double s = 0.0;
    #pragma unroll
    for (int c = 0; c < 16; ++c) s += colsp[((size_t)b*16 + c)*NCG + j];
    colsum[idx] = s;
}

__global__ void k_mnorm_out(const double* __restrict__ M, const double* __restrict__ colsum,
                            float* __restrict__ Mn) {
    size_t i = (size_t)blockIdx.x * blockDim.x + threadIdx.x;
    if (i >= (size_t)BB*NN*NCG) return;
    size_t b = i >> 16;
    int j = (int)(i & 63);
    Mn[i] = (float)(M[i] / colsum[b*NCG + j]);
}

// ---------------- H partials (f32) ----------------
__global__ __launch_bounds__(256) void k_Hpart32(const float* __restrict__ Mn,
                                                 const float* __restrict__ h,
                                                 float* __restrict__ Hp) {
    __shared__ float Ms[32*NCG];   // 8 KB
    __shared__ float hs[32*FF];    // 16 KB
    const int b = blockIdx.x, ch = blockIdx.y;
    const int tid = threadIdx.x;
    const int tc = tid % 32, tr = tid / 32;
    const float4* M4 = reinterpret_cast<const float4*>(Mn + (size_t)b*NN*NCG);
    const float4* h4 = reinterpret_cast<const float4*>(h + (size_t)b*NN*FF);
    float4* Ms4 = reinterpret_cast<float4*>(Ms);
    float4* hs4 = reinterpret_cast<float4*>(hs);
    const float2* Ms2 = reinterpret_cast<const float2*>(Ms);
    const float2* hs2 = reinterpret_cast<const float2*>(hs);

    float acc[8][4];
    #pragma unroll
    for (int i = 0; i < 8; ++i)
        #pragma unroll
        for (int j = 0; j < 4; ++j) acc[i][j] = 0.f;

    for (int s = 0; s < 4; ++s) {
        const int n0 = ch*128 + s*32;
        __syncthreads();
        #pragma unroll
        for (int i = 0; i < 2; ++i) Ms4[tid + i*256] = M4[n0*16 + tid + i*256];
        #pragma unroll
        for (int i = 0; i < 4; ++i) hs4[tid + i*256] = h4[n0*32 + tid + i*256];
        __syncthreads();
        for (int n = 0; n < 32; ++n) {
            float2 hv0 = hs2[n*64 + tc];
            float2 hv1 = hs2[n*64 + 32 + tc];
            float2 m0 = Ms2[n*32 + tr];
            float2 m1 = Ms2[n*32 + 8 + tr];
            float2 m2 = Ms2[n*32 + 16 + tr];
            float2 m3 = Ms2[n*32 + 24 + tr];
            float mj[8] = {m0.x, m0.y, m1.x, m1.y, m2.x, m2.y, m3.x, m3.y};
            #pragma unroll
            for (int jj = 0; jj < 8; ++jj) {
                acc[jj][0] += mj[jj]*hv0.x; acc[jj][1] += mj[jj]*hv0.y;
                acc[jj][2] += mj[jj]*hv1.x; acc[jj][3] += mj[jj]*hv1.y;
            }
        }
    }
    float* Ho = Hp + ((size_t)ch*BB + b) * NCG * FF;
    #pragma unroll
    for (int gj = 0; gj < 4; ++gj)
        #pragma unroll
        for (int pj = 0; pj < 2; ++pj) {
            int j = tr*2 + gj*16 + pj;
            int jj = gj*2 + pj;
            float2 o0; o0.x = acc[jj][0]; o0.y = acc[jj][1];
            float2 o1; o1.x = acc[jj][2]; o1.y = acc[jj][3];
            float2* op = reinterpret_cast<float2*>(Ho + (size_t)j*FF);
            op[tc] = o0; op[32 + tc] = o1;
        }
}

__global__ void k_Hfin32(const float* __restrict__ Hp, float* __restrict__ H) {
    int idx = blockIdx.x * blockDim.x + threadIdx.x;
    if (idx >= BB*NCG*FF) return;
    int b = idx / (NCG*FF);
    int r = idx % (NCG*FF);
    float s = 0.f;
    #pragma unroll
    for (int c = 0; c < 8; ++c) s += Hp[((size_t)c*BB + b)*NCG*FF + r];
    H[idx] = s;
}

// ---------------- cg partials (f64, feeds knbrs) ----------------
__global__ __launch_bounds__(192) void k_cgpart(const double* __restrict__ M,
                                                const float* __restrict__ xyz,
                                                double* __restrict__ cgp) {
    __shared__ double Ms[32*NCG];   // 16 KB
    __shared__ double xs[32*3];
    const int b = blockIdx.x, ch = blockIdx.y;
    const int tid = threadIdx.x;     // 192 = (j, d)
    const int j = tid / 3, d = tid % 3;
    const double2* M2 = reinterpret_cast<const double2*>(M + (size_t)b*NN*NCG);
    double2* Ms2 = reinterpret_cast<double2*>(Ms);
    const float* xb = xyz + (size_t)b*NN*3;
    double acc = 0.0;
    for (int s = 0; s < 4; ++s) {
        const int n0 = ch*128 + s*32;
        __syncthreads();
        for (int q = tid; q < 1024; q += 192) Ms2[q] = M2[n0*32 + q];
        for (int q = tid; q < 96; q += 192) xs[q] = (double)xb[n0*3 + q];
        __syncthreads();
        for (int n = 0; n < 32; ++n)
            acc += Ms[n*NCG + j] * xs[n*3 + d];
    }
    cgp[((size_t)ch*BB + b)*NCG*3 + tid] = acc;
}

__global__ void k_cgfin(const double* __restrict__ cgp, const double* __restrict__ colsum,
                        double* __restrict__ cg64, float* __restrict__ cg) {
    int idx = blockIdx.x * blockDim.x + threadIdx.x;
    if (idx >= BB*NCG*3) return;
    int b = idx / (NCG*3);
    int r = idx % (NCG*3);
    int j = r / 3;
    double s = 0.0;
    #pragma unroll
    for (int c = 0; c < 8; ++c) s += cgp[((size_t)c*BB + b)*NCG*3 + r];
    double v = s / colsum[b*NCG + j];
    cg64[idx] = v;
    cg[idx] = (float)v;
}

// ---------------- knbrs: rank-count argsort over squared distances ----------------
__global__ __launch_bounds__(1024) void k_knbrs(const double* __restrict__ cg,
                                                float* __restrict__ kn) {
    __shared__ double cs[NCG*3];
    const int b = blockIdx.x;
    const int tid = threadIdx.x;
    const int i = blockIdx.y * 16 + tid / 64;
    const int j = tid & 63;
    if (tid < NCG*3) cs[tid] = cg[(size_t)b*NCG*3 + tid];
    __syncthreads();
    double xi = cs[i*3+0], yi = cs[i*3+1], zi = cs[i*3+2];
    double dxj = xi - cs[j*3+0], dyj = yi - cs[j*3+1], dzj = zi - cs[j*3+2];
    double d2j = dxj*dxj + dyj*dyj + dzj*dzj;
    int rank = 0;
    for (int k = 0; k < NCG; ++k) {
        double dx = xi - cs[k*3+0], dy = yi - cs[k*3+1], dz = zi - cs[k*3+2];
        double d2k = dx*dx + dy*dy + dz*dz;
        rank += (d2k < d2j) || (d2k == d2j && k < j);
    }
    kn[(size_t)b*NCG*NCG + (size_t)i*NCG + rank] = (float)j;
}

// ---------------- adj (written LAST; region doubles as f64 scratch) ----------------
__global__ void k_zero_adj(float4* adj4, long n4) {
    long i = (long)blockIdx.x * blockDim.x + threadIdx.x;
    long stride = (long)gridDim.x * blockDim.x;
    float4 z; z.x = z.y = z.z = z.w = 0.f;
    for (; i < n4; i += stride) adj4[i] = z;
}

__global__ void k_bonds_adj(const int* __restrict__ bonds, int nb, float* adj) {
    int i = blockIdx.x * blockDim.x + threadIdx.x;
    if (i >= nb) return;
    int b = bonds[i*3+0], s = bonds[i*3+1], t = bonds[i*3+2];
    size_t base = (size_t)b * NN * NN;
    adj[base + (size_t)s*NN + t] = 1.f;
    adj[base + (size_t)t*NN + s] = 1.f;
}

extern "C" void kernel_launch(void* const* d_in, const int* in_sizes, int n_in,
                              void* d_out, int out_size, void* d_ws, size_t ws_size,
                              hipStream_t stream) {
    const int*   atoms  = (const int*)  d_in[0];
    const float* xyz    = (const float*)d_in[1];
    const int*   bonds  = (const int*)  d_in[2];
    const float* tau    = (const float*)d_in[3];
    const float* gum    = (const float*)d_in[4];
    const float* emb    = (const float*)d_in[5];
    const float* uW1    = (const float*)d_in[6];
    const float* ub1    = (const float*)d_in[7];
    const float* uW2    = (const float*)d_in[8];
    const float* ub2    = (const float*)d_in[9];
    const float* cgW1   = (const float*)d_in[10];
    const float* cgb1   = (const float*)d_in[11];
    const float* cgW2   = (const float*)d_in[12];
    const float* cgb2   = (const float*)d_in[13];

    float* out = (float*)d_out;
    float* o_M   = out + O_M;
    float* o_Mn  = out + O_MN;
    float* o_h   = out + O_H;
    float* o_H   = out + O_HH;
    float* o_adj = out + O_ADJ;
    float* o_cg  = out + O_CGXYZ;
    float* o_ca  = out + O_CGADJ;
    float* o_kn  = out + O_KN;

    double* scr   = (double*)o_adj;
    double* h64   = scr + S_H64;
    double* t64   = scr + S_T64;
    double* c64   = scr + S_C64;
    double* lm64  = scr + S_LM64;     // aliases h64 (h64 dead when written)
    double* colsp = scr + S_COLSP;    // aliases c64 (dead)
    float*  Hpf   = (float*)(scr + S_HPF);
    double* cgp   = scr + S_CGP;
    int*    nbr   = (int*)(scr + S_NBR);
    double* W64   = scr + S_W64;

    double* wsd    = (double*)d_ws;
    double* invdeg = wsd + W_INVD;
    double* colsum = wsd + W_COLS;
    double* cg64   = wsd + W_CG64;
    int*    cnt    = (int*)(wsd + W_CNT);

    const int nb = in_sizes[2] / 3;

    hipLaunchKernelGGL(k_zero, dim3(64), dim3(256), 0, stream, cnt);
    hipLaunchKernelGGL(k_build_nbr, dim3((nb+255)/256), dim3(256), 0, stream,
                       bonds, nb, cnt, nbr);
    hipLaunchKernelGGL(k_invdeg, dim3(64), dim3(256), 0, stream, cnt, invdeg);
    hipLaunchKernelGGL(k_cgadj, dim3(256), dim3(256), 0, stream, o_ca);
    hipLaunchKernelGGL(k_cvtW, dim3((W64_N+255)/256), dim3(256), 0, stream,
                       uW1, uW2, cgW1, cgW2, W64);
    hipLaunchKernelGGL(k_emb64, dim3(2048), dim3(256), 0, stream, atoms, emb, h64);

    for (int l = 0; l < NCONV; ++l) {
        hipLaunchKernelGGL((k_gemm64<128,true>), dim3(256,2), dim3(256), 0, stream,
                           h64, W64 + (size_t)l*32768, ub1 + (size_t)l*FF, t64);
        hipLaunchKernelGGL((k_gemm64<128,false>), dim3(256,2), dim3(256), 0, stream,
                           t64, W64 + (size_t)l*32768 + 16384, ub2 + (size_t)l*FF, c64);
        if (l < NCONV-1)
            hipLaunchKernelGGL((k_gather<false>), dim3(2048), dim3(256), 0, stream,
                               c64, invdeg, nbr, cnt, h64, o_h);
        else
            hipLaunchKernelGGL((k_gather<true>), dim3(2048), dim3(256), 0, stream,
                               c64, invdeg, nbr, cnt, h64, o_h);
    }

    hipLaunchKernelGGL((k_gemm64<128,true>), dim3(256,2), dim3(256), 0, stream,
                       h64, W64 + WO_CGW1, cgb1, t64);
    hipLaunchKernelGGL((k_gemm64<64,false>), dim3(256,1), dim3(256), 0, stream,
                       t64, W64 + WO_CGW2, cgb2, lm64);

    hipLaunchKernelGGL(k_softmax64, dim3(4096), dim3(256), 0, stream,
                       lm64, gum, tau, o_M);
    hipLaunchKernelGGL(k_cols_part, dim3(16,16), dim3(256), 0, stream, lm64, colsp);
    hipLaunchKernelGGL(k_cols_fin, dim3(4), dim3(256), 0, stream, colsp, colsum);
    hipLaunchKernelGGL(k_mnorm_out, dim3(4096), dim3(256), 0, stream, lm64, colsum, o_Mn);
    hipLaunchKernelGGL(k_Hpart32, dim3(BB, 8), dim3(256), 0, stream, o_Mn, o_h, Hpf);
    hipLaunchKernelGGL(k_Hfin32, dim3(512), dim3(256), 0, stream, Hpf, o_H);
    hipLaunchKernelGGL(k_cgpart, dim3(BB, 8), dim3(192), 0, stream, lm64, xyz, cgp);
    hipLaunchKernelGGL(k_cgfin, dim3(12), dim3(256), 0, stream, cgp, colsum, cg64, o_cg);
    hipLaunchKernelGGL(k_knbrs, dim3(BB, 4), dim3(1024), 0, stream, cg64, o_kn);

    // adj LAST: its region was scratch until here
    hipLaunchKernelGGL(k_zero_adj, dim3(4096), dim3(256), 0, stream,
                       (float4*)o_adj, (long)BB*NN*NN/4);
    hipLaunchKernelGGL(k_bonds_adj, dim3((nb+255)/256), dim3(256), 0, stream,
                       bonds, nb, o_adj);
}

// Round 7
// 369.777 us; speedup vs baseline: 1.2197x; 1.0812x over previous
//
#include <hip/hip_runtime.h>
#include <math.h>

// Problem constants
#define BB 16
#define NN 1024
#define FF 128
#define NCG 64
#define NCONV 3
#define CAP 8

typedef double f64x4 __attribute__((ext_vector_type(4)));

// ---- output layout (floats) ----
static const size_t O_M     = 0;
static const size_t O_MN    = (size_t)BB*NN*NCG;              // 1048576
static const size_t O_H     = O_MN  + (size_t)BB*NN*NCG;      // 2097152
static const size_t O_HH    = O_H   + (size_t)BB*NN*FF;       // 4194304
static const size_t O_ADJ   = O_HH  + (size_t)BB*NCG*FF;      // 4325376
static const size_t O_CGXYZ = O_ADJ + (size_t)BB*NN*NN;       // 21102592
static const size_t O_CGADJ = O_CGXYZ + (size_t)BB*NCG*3;     // 21105664
static const size_t O_KN    = O_CGADJ + (size_t)BB*NCG*NCG;   // 21171200

// f64 scratch aliased into adj output region (written last). adj = 8388608 doubles.
static const size_t S_H64   = 0;         // [B*N*F] = 2M doubles
static const size_t S_T64   = 2097152;   // [B*N*F]
static const size_t S_C64   = 4194304;   // [B*N*F] (gemm2 output; never in-place)
static const size_t S_LM64  = 0;         // aliases h64 (dead by then): [B*N*NCG] = 1M
static const size_t S_COLSP = 4194304;   // aliases c64 (dead): 16*16*64 doubles
static const size_t S_HPF   = 6291456;   // 16 x [B*NCG*F] floats = 1M doubles
static const size_t S_CGP   = 7340032;   // 32 x [B*NCG*3] doubles = 98304
static const size_t S_NBR   = 7438336;   // B*N*CAP ints = 65536 doubles
static const size_t S_W64   = 7503872;   // 122880 doubles
// end 7626752 < 8388608 OK

// W64 internal offsets (doubles)
static const size_t WO_CGW1 = 98304;
static const size_t WO_CGW2 = 114688;
static const int    W64_N   = 122880;

// ---- ws layout (doubles) ----
static const size_t W_INVD = 0;                                // [B*N]
static const size_t W_COLS = (size_t)BB*NN;                    // [B*NCG]
static const size_t W_CG64 = W_COLS + (size_t)BB*NCG;          // [B*NCG*3]
static const size_t W_CNT  = W_CG64 + (size_t)BB*NCG*3;        // B*N ints

// ---------------- init ----------------
__global__ void k_zero(int* cnt) {
    int i = blockIdx.x * blockDim.x + threadIdx.x;
    if (i < BB*NN) cnt[i] = 0;
}

__global__ void k_build_nbr(const int* __restrict__ bonds, int nb, int* cnt, int* nbr) {
    int i = blockIdx.x * blockDim.x + threadIdx.x;
    if (i >= nb) return;
    int b = bonds[i*3+0], s = bonds[i*3+1], t = bonds[i*3+2];
    int ns = b*NN + s, nt = b*NN + t;
    int p = atomicAdd(&cnt[ns], 1);
    if (p < CAP) nbr[(size_t)ns*CAP + p] = nt;
    int q = atomicAdd(&cnt[nt], 1);
    if (q < CAP) nbr[(size_t)nt*CAP + q] = ns;
}

__global__ void k_invdeg(const int* __restrict__ cnt, double* invdeg) {
    int i = blockIdx.x * blockDim.x + threadIdx.x;
    if (i >= BB*NN) return;
    int d = cnt[i];
    invdeg[i] = d > 0 ? 1.0 / (double)d : 0.0;
}

__global__ void k_cgadj(float* cgadj) {
    int idx = blockIdx.x * blockDim.x + threadIdx.x;
    if (idx >= BB*NCG*NCG) return;
    int i = (idx / NCG) % NCG, j = idx % NCG;
    cgadj[idx] = (i == j) ? 0.f : 1.f;
}

__global__ void k_emb64(const int* __restrict__ atoms, const float* __restrict__ emb,
                        double* __restrict__ h) {
    int idx = blockIdx.x * blockDim.x + threadIdx.x;
    if (idx >= BB*NN*(FF/4)) return;
    int n = idx / (FF/4), f4 = idx % (FF/4);
    int a = atoms[n];
    const float4 v = *reinterpret_cast<const float4*>(&emb[(size_t)a*FF + f4*4]);
    double* hp = &h[(size_t)n*FF + f4*4];
    hp[0] = (double)v.x; hp[1] = (double)v.y; hp[2] = (double)v.z; hp[3] = (double)v.w;
}

// weights f32 -> f64, once
__global__ void k_cvtW(const float* __restrict__ uW1, const float* __restrict__ uW2,
                       const float* __restrict__ cgW1, const float* __restrict__ cgW2,
                       double* __restrict__ W64) {
    int idx = blockIdx.x * blockDim.x + threadIdx.x;
    if (idx >= W64_N) return;
    float v;
    if (idx < 98304) {
        int l = idx >> 15, r = idx & 32767;
        v = (r < 16384) ? uW1[l*16384 + r] : uW2[l*16384 + (r & 16383)];
    } else if (idx < 114688) {
        v = cgW1[idx - 98304];
    } else {
        v = cgW2[idx - 114688];
    }
    W64[idx] = (double)v;
}

// ---------------- f64 MFMA GEMM: out = act(in @ W + b), K=128 ----------------
// 64-row x 64-col blocks, 4 waves, each wave: 16 rows x 64 cols via
// v_mfma_f64_16x16x4. Fragment layout: A[row=lane&15][k=lane>>4],
// B[k=lane>>4][col=lane&15], D reg i -> row=(lane>>4)*4+i, col=lane&15.
// grid = (rows/64, COUTT/64). Never in-place.
template<int COUTT, bool TANH>
__global__ __launch_bounds__(256) void k_gemm_mfma(const double* __restrict__ in,
                                                   const double* __restrict__ W,
                                                   const float* __restrict__ bias,
                                                   double* __restrict__ out) {
    constexpr int K = 128, KC = 32;
    constexpr int CT2 = COUTT/2;              // W row stride (double2)
    __shared__ double As[64*34];              // 17.4 KB (row stride 34)
    __shared__ double Ws[KC*66];              // 16.9 KB (row stride 66)
    const int tid = threadIdx.x;
    const int col0 = blockIdx.y * 64;
    const int C02 = col0 >> 1;
    const size_t row0 = (size_t)blockIdx.x * 64;
    const double2* in2 = reinterpret_cast<const double2*>(in + row0*K);
    const double2* Wg2 = reinterpret_cast<const double2*>(W);
    double2* As2 = reinterpret_cast<double2*>(As);
    double2* Ws2 = reinterpret_cast<double2*>(Ws);

    // prefetch chunk 0 into registers
    double2 pA[4], pW[4];
    #pragma unroll
    for (int i = 0; i < 4; ++i) { int q = tid + i*256; pA[i] = in2[(q>>4)*64 + (q&15)]; }
    #pragma unroll
    for (int i = 0; i < 4; ++i) { int q = tid + i*256; pW[i] = Wg2[(q>>5)*CT2 + C02 + (q&31)]; }

    const int lane = tid & 63;
    const int wv = tid >> 6;                  // wave 0..3 -> rows wv*16..+16
    const int m = lane & 15, kq = lane >> 4;
    const int arow = (wv*16 + m)*34 + kq;

    f64x4 acc[4];
    #pragma unroll
    for (int ct = 0; ct < 4; ++ct) acc[ct] = (f64x4){0.0, 0.0, 0.0, 0.0};

    for (int kc = 0; kc < K; kc += KC) {
        __syncthreads();   // prev chunk LDS reads complete
        #pragma unroll
        for (int i = 0; i < 4; ++i) { int q = tid + i*256; As2[(q>>4)*17 + (q&15)] = pA[i]; }
        #pragma unroll
        for (int i = 0; i < 4; ++i) { int q = tid + i*256; Ws2[(q>>5)*33 + (q&31)] = pW[i]; }
        if (kc + KC < K) {
            const int kn = kc + KC, kn2 = kn >> 1;
            #pragma unroll
            for (int i = 0; i < 4; ++i) { int q = tid + i*256; pA[i] = in2[(q>>4)*64 + kn2 + (q&15)]; }
            #pragma unroll
            for (int i = 0; i < 4; ++i) { int q = tid + i*256; pW[i] = Wg2[(kn + (q>>5))*CT2 + C02 + (q&31)]; }
        }
        __syncthreads();
        #pragma unroll
        for (int kk = 0; kk < KC; kk += 4) {
            double a = As[arow + kk];
            const double* wrow = Ws + (kk + kq)*66 + m;
            #pragma unroll
            for (int ct = 0; ct < 4; ++ct) {
                double b = wrow[ct*16];
                acc[ct] = __builtin_amdgcn_mfma_f64_16x16x4f64(a, b, acc[ct], 0, 0, 0);
            }
        }
    }

    const int orow = wv*16 + kq*4;
    #pragma unroll
    for (int ct = 0; ct < 4; ++ct) {
        int c = col0 + ct*16 + m;
        double bv = (double)bias[c];
        #pragma unroll
        for (int i = 0; i < 4; ++i) {
            double v = acc[ct][i] + bv;
            if (TANH) v = tanh(v);
            out[(row0 + orow + i)*COUTT + c] = v;
        }
    }
}

// ---------------- gather: h[node,:] += invdeg[node] * sum_nbr ch[nbr,:] ----------------
template<bool WRITE_F32>
__global__ void k_gather(const double* __restrict__ ch, const double* __restrict__ invdeg,
                         const int* __restrict__ nbr, const int* __restrict__ cnt,
                         double* __restrict__ h, float* __restrict__ hout) {
    int idx = blockIdx.x * blockDim.x + threadIdx.x;
    if (idx >= BB*NN*(FF/4)) return;
    int node = idx >> 5, f4 = idx & 31;
    int c = cnt[node];
    double2 s0; s0.x = 0.0; s0.y = 0.0;
    double2 s1 = s0;
    for (int q = 0; q < c; ++q) {
        int nb = nbr[(size_t)node*CAP + q];
        const double2* cp = reinterpret_cast<const double2*>(ch + (size_t)nb*FF + f4*4);
        double2 a = cp[0], b2 = cp[1];
        s0.x += a.x; s0.y += a.y; s1.x += b2.x; s1.y += b2.y;
    }
    double w = invdeg[node];
    double2* hp = reinterpret_cast<double2*>(h + (size_t)node*FF + f4*4);
    double2 h0 = hp[0], h1 = hp[1];
    h0.x += s0.x*w; h0.y += s0.y*w; h1.x += s1.x*w; h1.y += s1.y*w;
    hp[0] = h0; hp[1] = h1;
    if (WRITE_F32) {
        float4 o; o.x = (float)h0.x; o.y = (float)h0.y; o.z = (float)h1.x; o.w = (float)h1.y;
        *reinterpret_cast<float4*>(&hout[(size_t)node*FF + f4*4]) = o;
    }
}

// ---------------- gumbel softmax (f64, in-place logits->M), no atomics ----------------
__global__ void k_softmax64(double* __restrict__ lm, const float* __restrict__ gum,
                            const float* __restrict__ tau_p, float* __restrict__ M_out) {
    int row = blockIdx.x * 4 + threadIdx.x / 64;
    int lane = threadIdx.x & 63;
    double tau = (double)(*tau_p);
    double u = (double)gum[(size_t)row*NCG + lane];
    double g = -log(-log(u));
    double v = (lm[(size_t)row*NCG + lane] + g) / tau;
    double m = v;
    #pragma unroll
    for (int off = 32; off; off >>= 1) m = fmax(m, __shfl_xor(m, off));
    double e = exp(v - m);
    double s = e;
    #pragma unroll
    for (int off = 32; off; off >>= 1) s += __shfl_xor(s, off);
    double mv = e / s;
    lm[(size_t)row*NCG + lane] = mv;
    M_out[(size_t)row*NCG + lane] = (float)mv;
}

// deterministic chunked column sums: colsp[b,c,j] = sum_{n in chunk c} M[b,n,j]
__global__ __launch_bounds__(256) void k_cols_part(const double* __restrict__ M,
                                                   double* __restrict__ colsp) {
    __shared__ double red[256];
    const int b = blockIdx.x, c = blockIdx.y;
    const int tid = threadIdx.x;
    const int j = tid & 63, q = tid >> 6;
    const double* Mb = M + (size_t)b*NN*NCG + (size_t)(c*64 + q*16)*NCG;
    double s = 0.0;
    #pragma unroll
    for (int r = 0; r < 16; ++r) s += Mb[(size_t)r*NCG + j];
    red[tid] = s;
    __syncthreads();
    if (tid < 64)
        colsp[((size_t)b*16 + c)*NCG + j] = red[j] + red[64+j] + red[128+j] + red[192+j];
}

__global__ void k_cols_fin(const double* __restrict__ colsp, double* __restrict__ colsum) {
    int idx = blockIdx.x * blockDim.x + threadIdx.x;
    if (idx >= BB*NCG) return;
    int b = idx >> 6, j = idx & 63;
    double s = 0.0;
    #pragma unroll
    for (int c = 0; c < 16; ++c) s += colsp[((size_t)b*16 + c)*NCG + j];
    colsum[idx] = s;
}

__global__ void k_mnorm_out(const double* __restrict__ M, const double* __restrict__ colsum,
                            float* __restrict__ Mn) {
    size_t i = (size_t)blockIdx.x * blockDim.x + threadIdx.x;
    if (i >= (size_t)BB*NN*NCG) return;
    size_t b = i >> 16;
    int j = (int)(i & 63);
    Mn[i] = (float)(M[i] / colsum[b*NCG + j]);
}

// ---------------- H partials (f32): 16 chunks of 64 rows ----------------
__global__ __launch_bounds__(256) void k_Hpart32(const float* __restrict__ Mn,
                                                 const float* __restrict__ h,
                                                 float* __restrict__ Hp) {
    __shared__ float Ms[32*NCG];   // 8 KB
    __shared__ float hs[32*FF];    // 16 KB
    const int b = blockIdx.x, ch = blockIdx.y;
    const int tid = threadIdx.x;
    const int tc = tid % 32, tr = tid / 32;
    const float4* M4 = reinterpret_cast<const float4*>(Mn + (size_t)b*NN*NCG);
    const float4* h4 = reinterpret_cast<const float4*>(h + (size_t)b*NN*FF);
    float4* Ms4 = reinterpret_cast<float4*>(Ms);
    float4* hs4 = reinterpret_cast<float4*>(hs);
    const float2* Ms2 = reinterpret_cast<const float2*>(Ms);
    const float2* hs2 = reinterpret_cast<const float2*>(hs);

    float acc[8][4];
    #pragma unroll
    for (int i = 0; i < 8; ++i)
        #pragma unroll
        for (int j = 0; j < 4; ++j) acc[i][j] = 0.f;

    for (int s = 0; s < 2; ++s) {
        const int n0 = ch*64 + s*32;
        __syncthreads();
        #pragma unroll
        for (int i = 0; i < 2; ++i) Ms4[tid + i*256] = M4[n0*16 + tid + i*256];
        #pragma unroll
        for (int i = 0; i < 4; ++i) hs4[tid + i*256] = h4[n0*32 + tid + i*256];
        __syncthreads();
        for (int n = 0; n < 32; ++n) {
            float2 hv0 = hs2[n*64 + tc];
            float2 hv1 = hs2[n*64 + 32 + tc];
            float2 m0 = Ms2[n*32 + tr];
            float2 m1 = Ms2[n*32 + 8 + tr];
            float2 m2 = Ms2[n*32 + 16 + tr];
            float2 m3 = Ms2[n*32 + 24 + tr];
            float mj[8] = {m0.x, m0.y, m1.x, m1.y, m2.x, m2.y, m3.x, m3.y};
            #pragma unroll
            for (int jj = 0; jj < 8; ++jj) {
                acc[jj][0] += mj[jj]*hv0.x; acc[jj][1] += mj[jj]*hv0.y;
                acc[jj][2] += mj[jj]*hv1.x; acc[jj][3] += mj[jj]*hv1.y;
            }
        }
    }
    float* Ho = Hp + ((size_t)ch*BB + b) * NCG * FF;
    #pragma unroll
    for (int gj = 0; gj < 4; ++gj)
        #pragma unroll
        for (int pj = 0; pj < 2; ++pj) {
            int j = tr*2 + gj*16 + pj;
            int jj = gj*2 + pj;
            float2 o0; o0.x = acc[jj][0]; o0.y = acc[jj][1];
            float2 o1; o1.x = acc[jj][2]; o1.y = acc[jj][3];
            float2* op = reinterpret_cast<float2*>(Ho + (size_t)j*FF);
            op[tc] = o0; op[32 + tc] = o1;
        }
}

__global__ void k_Hfin32(const float* __restrict__ Hp, float* __restrict__ H) {
    int idx = blockIdx.x * blockDim.x + threadIdx.x;
    if (idx >= BB*NCG*FF) return;
    int b = idx / (NCG*FF);
    int r = idx % (NCG*FF);
    float s = 0.f;
    #pragma unroll
    for (int c = 0; c < 16; ++c) s += Hp[((size_t)c*BB + b)*NCG*FF + r];
    H[idx] = s;
}

// ---------------- cg partials (f64, feeds knbrs): 32 chunks of 32 rows ----------------
__global__ __launch_bounds__(192) void k_cgpart(const double* __restrict__ M,
                                                const float* __restrict__ xyz,
                                                double* __restrict__ cgp) {
    __shared__ double Ms[32*NCG];   // 16 KB
    __shared__ double xs[32*3];
    const int b = blockIdx.x, ch = blockIdx.y;   // ch 0..31
    const int tid = threadIdx.x;                 // 192 = (j, d)
    const int j = tid / 3, d = tid % 3;
    const int n0 = ch*32;
    const double2* M2 = reinterpret_cast<const double2*>(M + (size_t)b*NN*NCG);
    double2* Ms2 = reinterpret_cast<double2*>(Ms);
    const float* xb = xyz + (size_t)b*NN*3;
    for (int q = tid; q < 1024; q += 192) Ms2[q] = M2[n0*32 + q];
    for (int q = tid; q < 96; q += 192) xs[q] = (double)xb[n0*3 + q];
    __syncthreads();
    double acc = 0.0;
    #pragma unroll 8
    for (int n = 0; n < 32; ++n) acc += Ms[n*NCG + j] * xs[n*3 + d];
    cgp[((size_t)ch*BB + b)*192 + tid] = acc;
}

__global__ void k_cgfin(const double* __restrict__ cgp, const double* __restrict__ colsum,
                        double* __restrict__ cg64, float* __restrict__ cg) {
    int idx = blockIdx.x * blockDim.x + threadIdx.x;
    if (idx >= BB*NCG*3) return;
    int b = idx / (NCG*3);
    int r = idx % (NCG*3);
    int j = r / 3;
    double s = 0.0;
    #pragma unroll
    for (int c = 0; c < 32; ++c) s += cgp[((size_t)c*BB + b)*192 + r];
    double v = s / colsum[b*NCG + j];
    cg64[idx] = v;
    cg[idx] = (float)v;
}

// ---------------- knbrs: rank-count argsort over squared distances ----------------
__global__ __launch_bounds__(1024) void k_knbrs(const double* __restrict__ cg,
                                                float* __restrict__ kn) {
    __shared__ double cs[NCG*3];
    const int b = blockIdx.x;
    const int tid = threadIdx.x;
    const int i = blockIdx.y * 16 + tid / 64;
    const int j = tid & 63;
    if (tid < NCG*3) cs[tid] = cg[(size_t)b*NCG*3 + tid];
    __syncthreads();
    double xi = cs[i*3+0], yi = cs[i*3+1], zi = cs[i*3+2];
    double dxj = xi - cs[j*3+0], dyj = yi - cs[j*3+1], dzj = zi - cs[j*3+2];
    double d2j = dxj*dxj + dyj*dyj + dzj*dzj;
    int rank = 0;
    for (int k = 0; k < NCG; ++k) {
        double dx = xi - cs[k*3+0], dy = yi - cs[k*3+1], dz = zi - cs[k*3+2];
        double d2k = dx*dx + dy*dy + dz*dz;
        rank += (d2k < d2j) || (d2k == d2j && k < j);
    }
    kn[(size_t)b*NCG*NCG + (size_t)i*NCG + rank] = (float)j;
}

// ---------------- adj (written LAST; region doubles as f64 scratch) ----------------
__global__ void k_zero_adj(float4* adj4, long n4) {
    long i = (long)blockIdx.x * blockDim.x + threadIdx.x;
    long stride = (long)gridDim.x * blockDim.x;
    float4 z; z.x = z.y = z.z = z.w = 0.f;
    for (; i < n4; i += stride) adj4[i] = z;
}

__global__ void k_bonds_adj(const int* __restrict__ bonds, int nb, float* adj) {
    int i = blockIdx.x * blockDim.x + threadIdx.x;
    if (i >= nb) return;
    int b = bonds[i*3+0], s = bonds[i*3+1], t = bonds[i*3+2];
    size_t base = (size_t)b * NN * NN;
    adj[base + (size_t)s*NN + t] = 1.f;
    adj[base + (size_t)t*NN + s] = 1.f;
}

extern "C" void kernel_launch(void* const* d_in, const int* in_sizes, int n_in,
                              void* d_out, int out_size, void* d_ws, size_t ws_size,
                              hipStream_t stream) {
    const int*   atoms  = (const int*)  d_in[0];
    const float* xyz    = (const float*)d_in[1];
    const int*   bonds  = (const int*)  d_in[2];
    const float* tau    = (const float*)d_in[3];
    const float* gum    = (const float*)d_in[4];
    const float* emb    = (const float*)d_in[5];
    const float* uW1    = (const float*)d_in[6];
    const float* ub1    = (const float*)d_in[7];
    const float* uW2    = (const float*)d_in[8];
    const float* ub2    = (const float*)d_in[9];
    const float* cgW1   = (const float*)d_in[10];
    const float* cgb1   = (const float*)d_in[11];
    const float* cgW2   = (const float*)d_in[12];
    const float* cgb2   = (const float*)d_in[13];

    float* out = (float*)d_out;
    float* o_M   = out + O_M;
    float* o_Mn  = out + O_MN;
    float* o_h   = out + O_H;
    float* o_H   = out + O_HH;
    float* o_adj = out + O_ADJ;
    float* o_cg  = out + O_CGXYZ;
    float* o_ca  = out + O_CGADJ;
    float* o_kn  = out + O_KN;

    double* scr   = (double*)o_adj;
    double* h64   = scr + S_H64;
    double* t64   = scr + S_T64;
    double* c64   = scr + S_C64;
    double* lm64  = scr + S_LM64;     // aliases h64 (h64 dead when written)
    double* colsp = scr + S_COLSP;    // aliases c64 (dead)
    float*  Hpf   = (float*)(scr + S_HPF);
    double* cgp   = scr + S_CGP;
    int*    nbr   = (int*)(scr + S_NBR);
    double* W64   = scr + S_W64;

    double* wsd    = (double*)d_ws;
    double* invdeg = wsd + W_INVD;
    double* colsum = wsd + W_COLS;
    double* cg64   = wsd + W_CG64;
    int*    cnt    = (int*)(wsd + W_CNT);

    const int nb = in_sizes[2] / 3;

    hipLaunchKernelGGL(k_zero, dim3(64), dim3(256), 0, stream, cnt);
    hipLaunchKernelGGL(k_build_nbr, dim3((nb+255)/256), dim3(256), 0, stream,
                       bonds, nb, cnt, nbr);
    hipLaunchKernelGGL(k_invdeg, dim3(64), dim3(256), 0, stream, cnt, invdeg);
    hipLaunchKernelGGL(k_cgadj, dim3(256), dim3(256), 0, stream, o_ca);
    hipLaunchKernelGGL(k_cvtW, dim3((W64_N+255)/256), dim3(256), 0, stream,
                       uW1, uW2, cgW1, cgW2, W64);
    hipLaunchKernelGGL(k_emb64, dim3(2048), dim3(256), 0, stream, atoms, emb, h64);

    for (int l = 0; l < NCONV; ++l) {
        hipLaunchKernelGGL((k_gemm_mfma<128,true>), dim3(256,2), dim3(256), 0, stream,
                           h64, W64 + (size_t)l*32768, ub1 + (size_t)l*FF, t64);
        hipLaunchKernelGGL((k_gemm_mfma<128,false>), dim3(256,2), dim3(256), 0, stream,
                           t64, W64 + (size_t)l*32768 + 16384, ub2 + (size_t)l*FF, c64);
        if (l < NCONV-1)
            hipLaunchKernelGGL((k_gather<false>), dim3(2048), dim3(256), 0, stream,
                               c64, invdeg, nbr, cnt, h64, o_h);
        else
            hipLaunchKernelGGL((k_gather<true>), dim3(2048), dim3(256), 0, stream,
                               c64, invdeg, nbr, cnt, h64, o_h);
    }

    hipLaunchKernelGGL((k_gemm_mfma<128,true>), dim3(256,2), dim3(256), 0, stream,
                       h64, W64 + WO_CGW1, cgb1, t64);
    hipLaunchKernelGGL((k_gemm_mfma<64,false>), dim3(256,1), dim3(256), 0, stream,
                       t64, W64 + WO_CGW2, cgb2, lm64);

    hipLaunchKernelGGL(k_softmax64, dim3(4096), dim3(256), 0, stream,
                       lm64, gum, tau, o_M);
    hipLaunchKernelGGL(k_cols_part, dim3(16,16), dim3(256), 0, stream, lm64, colsp);
    hipLaunchKernelGGL(k_cols_fin, dim3(4), dim3(256), 0, stream, colsp, colsum);
    hipLaunchKernelGGL(k_mnorm_out, dim3(4096), dim3(256), 0, stream, lm64, colsum, o_Mn);
    hipLaunchKernelGGL(k_Hpart32, dim3(BB, 16), dim3(256), 0, stream, o_Mn, o_h, Hpf);
    hipLaunchKernelGGL(k_Hfin32, dim3(512), dim3(256), 0, stream, Hpf, o_H);
    hipLaunchKernelGGL(k_cgpart, dim3(BB, 32), dim3(192), 0, stream, lm64, xyz, cgp);
    hipLaunchKernelGGL(k_cgfin, dim3(12), dim3(256), 0, stream, cgp, colsum, cg64, o_cg);
    hipLaunchKernelGGL(k_knbrs, dim3(BB, 4), dim3(1024), 0, stream, cg64, o_kn);

    // adj LAST: its region was scratch until here
    hipLaunchKernelGGL(k_zero_adj, dim3(4096), dim3(256), 0, stream,
                       (float4*)o_adj, (long)BB*NN*NN/4);
    hipLaunchKernelGGL(k_bonds_adj, dim3((nb+255)/256), dim3(256), 0, stream,
                       bonds, nb, o_adj);
}